// Round 2
// baseline (181076.819 us; speedup 1.0000x reference)
//
#include <hip/hip_runtime.h>
#include <cstdint>
#include <cstddef>

// Decoder (LFADS-like): B=512, T=200.
// Persistent single kernel: 512 blocks x 256 threads, all co-resident.
// Per step: 4 dependent bf16-MFMA GEMM stages separated by device-wide
// two-level barriers (800 grid syncs total). Staging via global_load_lds
// width 16 with pre-swizzled source (bank-conflict-free ds_read_b128).
// Precomposed weights:
//   W'  = com_W @ gen_K[:32]    (co_mean folded into generator input GEMM)
//   W'' = fac_Wn @ con_K[128:]  (factor path folded into controller GEMM;
//                                fac_Wn columns appended -> facs output free)

#define B_   512
#define T_   200
#define CI_  128
#define EXT_ 8
#define GEN_ 800
#define CON_ 400
#define CO_  32
#define FAC_ 128
#define NBLK 512

typedef __attribute__((ext_vector_type(8))) short short8;
typedef __attribute__((ext_vector_type(4))) float f32x4;
typedef __attribute__((ext_vector_type(4))) unsigned short us4;

typedef __attribute__((address_space(1))) void as1v;
typedef __attribute__((address_space(3))) void as3v;

__device__ __forceinline__ unsigned short f2bf(float f) {
  unsigned int u = __float_as_uint(f);
  u += 0x7FFFu + ((u >> 16) & 1u);   // RNE
  return (unsigned short)(u >> 16);
}
__device__ __forceinline__ float sigm(float x) { return 1.0f / (1.0f + __expf(-x)); }

__device__ __forceinline__ void gload16(const void* g, void* l) {
  __builtin_amdgcn_global_load_lds((as1v*)g, (as3v*)l, 16, 0, 0);
}

// ---------------- setup kernels ----------------

__global__ void k_facnorm(const float* __restrict__ facW, float* __restrict__ facWn) {
  int j = blockIdx.x;            // 0..127 (column)
  int l = threadIdx.x;           // 64 threads = 1 wave
  float s = 0.f;
  for (int k = l; k < GEN_; k += 64) { float v = facW[(size_t)k*FAC_ + j]; s += v*v; }
  #pragma unroll
  for (int off = 32; off > 0; off >>= 1) s += __shfl_down(s, off, 64);
  float inv = 1.0f / sqrtf(__shfl(s, 0, 64));
  for (int k = l; k < GEN_; k += 64) facWn[(size_t)k*FAC_ + j] = facW[(size_t)k*FAC_ + j] * inv;
}

// tmp2[kp][n] = sum_j facWn[kp][j] * conK[128+j][n]   (kp<800, n<1200)
__global__ void k_w2(const float* __restrict__ facWn, const float* __restrict__ conK,
                     float* __restrict__ tmp2) {
  int n = blockIdx.x*256 + threadIdx.x; if (n >= 1200) return;
  int kp = blockIdx.y;
  const float* fr = facWn + (size_t)kp*FAC_;
  float s = 0.f;
  for (int j = 0; j < FAC_; ++j) s = fmaf(fr[j], conK[(size_t)(CI_+j)*1200 + n], s);
  tmp2[(size_t)kp*1200 + n] = s;
}

// tmp1[k][n] = sum_j comW[k][j] * genK[j][n]   (k<400, n<2400)
__global__ void k_w1(const float* __restrict__ comW, const float* __restrict__ genK,
                     float* __restrict__ tmp1) {
  int n = blockIdx.x*256 + threadIdx.x; if (n >= 2400) return;
  int k = blockIdx.y;
  const float* cr = comW + (size_t)k*CO_;
  float s = 0.f;
  for (int j = 0; j < CO_; ++j) s = fmaf(cr[j], genK[(size_t)j*2400 + n], s);
  tmp1[(size_t)k*2400 + n] = s;
}

__global__ void k_cvt(const float* __restrict__ ci, const float* __restrict__ ext,
                      unsigned short* __restrict__ cib, unsigned short* __restrict__ extb) {
  const long n1 = (long)B_*T_*CI_/4;
  const long n2 = (long)B_*T_*EXT_/4;
  for (long i = blockIdx.x*(long)blockDim.x + threadIdx.x; i < n1+n2;
       i += (long)gridDim.x*blockDim.x) {
    if (i < n1) {
      float4 f = reinterpret_cast<const float4*>(ci)[i];
      us4 u; u.x=f2bf(f.x); u.y=f2bf(f.y); u.z=f2bf(f.z); u.w=f2bf(f.w);
      reinterpret_cast<us4*>(cib)[i] = u;
    } else {
      long k = i - n1;
      float4 f = reinterpret_cast<const float4*>(ext)[k];
      us4 u; u.x=f2bf(f.x); u.y=f2bf(f.y); u.z=f2bf(f.z); u.w=f2bf(f.w);
      reinterpret_cast<us4*>(extb)[k] = u;
    }
  }
}

__global__ void k_init(const float* __restrict__ conh0, const float* __restrict__ geninit,
                       const float* __restrict__ conb, const float* __restrict__ genb,
                       const float* __restrict__ comb, const float* __restrict__ genK,
                       float* __restrict__ bczr, float* __restrict__ bgzr,
                       float* __restrict__ conh, unsigned short* __restrict__ agzr,
                       float* __restrict__ genh, unsigned short* __restrict__ genhb,
                       unsigned short* __restrict__ achh,
                       unsigned short* __restrict__ zbuf, unsigned* __restrict__ gs) {
  const long R0=1344, R1=2432, R2=(long)B_*CON_, R3=(long)B_*CON_,
             R4=(long)B_*GEN_, R5=(long)B_*GEN_, R6=(long)B_*416, R7=64, R8=320;
  const long total = R0+R1+R2+R3+R4+R5+R6+R7+R8;
  for (long idx = blockIdx.x*(long)blockDim.x + threadIdx.x; idx < total;
       idx += (long)gridDim.x*blockDim.x) {
    long i = idx;
    if (i < R0) { bczr[i] = (i < 1200) ? conb[i] : 0.f; continue; }
    i -= R0;
    if (i < R1) {
      float s = 0.f;
      if (i < 2400) { s = genb[i]; for (int j=0;j<32;++j) s = fmaf(comb[j], genK[(size_t)j*2400 + i], s); }
      bgzr[i] = s; continue;
    }
    i -= R1;
    if (i < R2) { conh[i] = conh0[i % CON_]; continue; }
    i -= R2;
    if (i < R3) { agzr[i] = f2bf(conh0[i % CON_]); continue; }
    i -= R3;
    if (i < R4) { genh[i] = geninit[i]; continue; }
    i -= R4;
    if (i < R5) { genhb[i] = f2bf(geninit[i]); continue; }
    i -= R5;
    if (i < R6) { achh[i] = 0; continue; }
    i -= R6;
    if (i < R7) { zbuf[i] = 0; continue; }
    i -= R7;
    gs[i] = 0;
  }
}

// build transposed bf16 weights: dst[n][k] = fetch(k, n)
struct BTArgs {
  int mode, K;
  const float* conK; const float* conR; const float* genK; const float* genR;
  const float* facWn; const float* tmp1; const float* tmp2;
  unsigned short* dst;
};

__device__ __forceinline__ float bt_fetch(const BTArgs& a, int k, int n) {
  switch (a.mode) {
    case 0: // W_czr^T: K=1344 (ci128|gen800|con416), N=1344 (z400|r400|xh400|fac128|pad)
      if (n < 1200) {
        if (k < 128)  return a.conK[(size_t)k*1200 + n];
        if (k < 928)  return a.tmp2[(size_t)(k-128)*1200 + n];
        if (k < 1328) return (n < 800) ? a.conR[(size_t)(k-928)*1200 + n] : 0.f;
        return 0.f;
      }
      if (n < 1328) return (k >= 128 && k < 928) ? a.facWn[(size_t)(k-128)*FAC_ + (n-1200)] : 0.f;
      return 0.f;
    case 1: // W_chh^T: con_R[:,800:1200]
      return (k < 400 && n < 400) ? a.conR[(size_t)k*1200 + 800 + n] : 0.f;
    case 2: // W_gzr^T: K=1216 (conh400|ext8|pad8|genh800), N=2432 (z800|r800|xh800|pad)
      if (n >= 2400) return 0.f;
      if (k < 400)  return a.tmp1[(size_t)k*2400 + n];
      if (k < 408)  return a.genK[(size_t)(32 + k - 400)*2400 + n];
      if (k < 416)  return 0.f;
      if (k < 1216) return (n < 1600) ? a.genR[(size_t)(k-416)*2400 + n] : 0.f;
      return 0.f;
    case 3: // W_ghh^T: gen_R[:,1600:2400]
      return (n < 800 && k < 800) ? a.genR[(size_t)k*2400 + 1600 + n] : 0.f;
    default: // fac_Wn^T [128][800]
      return (k < 800 && n < 128) ? a.facWn[(size_t)k*FAC_ + n] : 0.f;
  }
}

__global__ __launch_bounds__(256) void k_buildT(BTArgs a) {
  __shared__ float tile[64][65];
  int k0 = blockIdx.x*64, n0 = blockIdx.y*64;
  int tid = threadIdx.x;
  int rr = tid >> 2, cc = (tid & 3) * 16;
  #pragma unroll 4
  for (int i = 0; i < 16; ++i) tile[rr][cc+i] = bt_fetch(a, k0+rr, n0+cc+i);
  __syncthreads();
  int n = n0 + rr;
  if (k0 + cc < a.K) {    // K is a multiple of 16
    short8 v0, v1;
    #pragma unroll
    for (int i = 0; i < 8; ++i) v0[i] = (short)f2bf(tile[cc+i][rr]);
    #pragma unroll
    for (int i = 0; i < 8; ++i) v1[i] = (short)f2bf(tile[cc+8+i][rr]);
    *reinterpret_cast<short8*>(&a.dst[(size_t)n*a.K + k0 + cc])     = v0;
    *reinterpret_cast<short8*>(&a.dst[(size_t)n*a.K + k0 + cc + 8]) = v1;
  }
}

// ---------------- persistent decoder kernel ----------------

struct PA {
  const unsigned short* cib; const unsigned short* extb;
  const unsigned short* wczr; const unsigned short* wchh; const unsigned short* wgzr;
  const unsigned short* wghh; const unsigned short* wfac;
  const float* bczr; const float* bgzr;
  float* zcon; float* xhcon; float* zgen; float* xhgen;
  float* conh; float* genh;
  unsigned short* genhb; unsigned short* agzr; unsigned short* achh; unsigned short* aghh;
  const unsigned short* zbuf;
  float* out;
  unsigned* gs;   // [0,32,..,224]=group counters, [256]=root, [288]=flag
};

enum { S_CZR=0, S_CHH=1, S_GZR=2, S_GHH=3, S_FAC=4 };

__device__ __forceinline__ void gbar(unsigned* gs, unsigned epoch) {
  __syncthreads();
  if (threadIdx.x == 0) {
    __threadfence();
    const int grp = blockIdx.x >> 6;   // 8 groups of 64 blocks
    unsigned p = __hip_atomic_fetch_add(&gs[grp*32], 1u, __ATOMIC_ACQ_REL, __HIP_MEMORY_SCOPE_AGENT);
    if (p + 1u == 64u * epoch) {
      unsigned q = __hip_atomic_fetch_add(&gs[256], 1u, __ATOMIC_ACQ_REL, __HIP_MEMORY_SCOPE_AGENT);
      if (q + 1u == 8u * epoch)
        __hip_atomic_store(&gs[288], epoch, __ATOMIC_RELEASE, __HIP_MEMORY_SCOPE_AGENT);
    }
    unsigned v = __hip_atomic_load(&gs[288], __ATOMIC_ACQUIRE, __HIP_MEMORY_SCOPE_AGENT);
    long guard = 0;
    while ((int)(v - epoch) < 0 && ++guard < 200000000L) {
      __builtin_amdgcn_s_sleep(4);
      v = __hip_atomic_load(&gs[288], __ATOMIC_ACQUIRE, __HIP_MEMORY_SCOPE_AGENT);
    }
    __threadfence();
  }
  __syncthreads();
}

template<int STAGE, int K, int NN, int PER>
__device__ __forceinline__ void do_stage(const PA& a, int t,
                                         unsigned short (&sA)[2][2048],
                                         unsigned short (&sB)[2][2048]) {
  const int b = blockIdx.x;
  const int xx = b & 7, j = b >> 3;
  if (j >= 8 * PER) return;
  const int bn = xx + 8 * (j % PER);
  const int bm = j / PER;
  if (bn >= NN) return;

  const unsigned short* w =
      STAGE == S_CZR ? a.wczr : STAGE == S_CHH ? a.wchh :
      STAGE == S_GZR ? a.wgzr : STAGE == S_GHH ? a.wghh : a.wfac;

  const int tid = threadIdx.x, lane = tid & 63, wid = tid >> 6;
  const int wm = wid >> 1, wn = wid & 1;
  const int srow = tid >> 2;                       // 0..63 (tile row staged by this thread)
  const int scb  = (tid & 3) ^ ((tid >> 3) & 3);   // pre-swizzled source 16B block
  const int brow = bm * 64 + srow;                 // batch row (A side)
  const unsigned short* wrow = w + (size_t)(bn * 64 + srow) * K;

  f32x4 acc[2][2];
  #pragma unroll
  for (int i=0;i<2;++i)
    #pragma unroll
    for (int jj=0;jj<2;++jj) acc[i][jj] = (f32x4){0.f,0.f,0.f,0.f};

  auto issue = [&](int buf, int kt) {
    const int e = kt * 32 + scb * 8;
    const unsigned short* pa;
    if constexpr (STAGE == S_CZR) {
      const unsigned short* p0 = a.cib   + ((size_t)brow*T_ + t)*CI_ + e;
      const unsigned short* p1 = a.genhb + (size_t)brow*GEN_ + (e - 128);
      const unsigned short* p2 = a.agzr  + (size_t)brow*CON_ + (e - 928);
      pa = e < 128 ? p0 : (e < 928 ? p1 : (e < 1328 ? p2 : a.zbuf));
    } else if constexpr (STAGE == S_CHH) {
      pa = a.achh + (size_t)brow*416 + e;
    } else if constexpr (STAGE == S_GZR) {
      const unsigned short* p0 = a.agzr  + (size_t)brow*CON_ + e;
      const unsigned short* p1 = a.extb  + ((size_t)brow*T_ + t)*EXT_;
      const unsigned short* p2 = a.genhb + (size_t)brow*GEN_ + (e - 416);
      pa = e < 400 ? p0 : (e < 408 ? p1 : (e < 416 ? (const unsigned short*)a.zbuf : p2));
    } else if constexpr (STAGE == S_GHH) {
      pa = a.aghh + (size_t)brow*GEN_ + e;
    } else { // S_FAC
      pa = a.genhb + (size_t)brow*GEN_ + e;
    }
    gload16(pa,       &sA[buf][wid * 512]);
    gload16(wrow + e, &sB[buf][wid * 512]);
  };

  constexpr int NK = K / 32;
  issue(0, 0);
  const int l15 = lane & 15, lb = lane >> 4;
  for (int kt = 0; kt < NK; ++kt) {
    const int cur = kt & 1;
    if (kt + 1 < NK) {
      issue(cur ^ 1, kt + 1);
      asm volatile("s_waitcnt vmcnt(2)" ::: "memory");
    } else {
      asm volatile("s_waitcnt vmcnt(0)" ::: "memory");
    }
    asm volatile("s_barrier" ::: "memory");
    // swizzled ds_read: row r, logical block c -> physical block c ^ ((r>>1)&3)
    const int rA0 = wm*32 + l15,      rA1 = rA0 + 16;
    const int rB0 = wn*32 + l15,      rB1 = rB0 + 16;
    short8 a0 = *(const short8*)&sA[cur][rA0*32 + ((lb ^ ((rA0>>1)&3))*8)];
    short8 a1 = *(const short8*)&sA[cur][rA1*32 + ((lb ^ ((rA1>>1)&3))*8)];
    short8 b0 = *(const short8*)&sB[cur][rB0*32 + ((lb ^ ((rB0>>1)&3))*8)];
    short8 b1 = *(const short8*)&sB[cur][rB1*32 + ((lb ^ ((rB1>>1)&3))*8)];
    acc[0][0] = __builtin_amdgcn_mfma_f32_16x16x32_bf16(a0, b0, acc[0][0], 0,0,0);
    acc[0][1] = __builtin_amdgcn_mfma_f32_16x16x32_bf16(a0, b1, acc[0][1], 0,0,0);
    acc[1][0] = __builtin_amdgcn_mfma_f32_16x16x32_bf16(a1, b0, acc[1][0], 0,0,0);
    acc[1][1] = __builtin_amdgcn_mfma_f32_16x16x32_bf16(a1, b1, acc[1][1], 0,0,0);
    asm volatile("s_waitcnt lgkmcnt(0)" ::: "memory");
    asm volatile("s_barrier" ::: "memory");
  }

  const int lrow = (lane >> 4) * 4;
  #pragma unroll
  for (int mi=0; mi<2; ++mi)
  #pragma unroll
  for (int ni=0; ni<2; ++ni)
  #pragma unroll
  for (int jj=0; jj<4; ++jj) {
    int bb = bm*64 + wm*32 + mi*16 + lrow + jj;
    int c  = bn*64 + wn*32 + ni*16 + l15;
    float v = acc[mi][ni][jj];
    if constexpr (STAGE == S_CZR) {
      if (c < 400) {
        a.zcon[(size_t)bb*CON_ + c] = sigm(v + a.bczr[c]);
      } else if (c < 800) {
        int u = c - 400;
        a.achh[(size_t)bb*416 + u] = f2bf(sigm(v + a.bczr[c]) * a.conh[(size_t)bb*CON_ + u]);
      } else if (c < 1200) {
        a.xhcon[(size_t)bb*CON_ + (c-800)] = v + a.bczr[c];
      } else if (c < 1328) {
        if (t > 0) a.out[((size_t)bb*T_ + (t-1))*FAC_ + (c-1200)] = v;
      }
    } else if constexpr (STAGE == S_CHH) {
      if (c < 400) {
        float hh = tanhf(v + a.xhcon[(size_t)bb*CON_ + c]);
        float z  = a.zcon[(size_t)bb*CON_ + c];
        float h  = z * a.conh[(size_t)bb*CON_ + c] + (1.f - z) * hh;
        h = fminf(fmaxf(h, -5.f), 5.f);
        a.conh[(size_t)bb*CON_ + c] = h;
        a.agzr[(size_t)bb*CON_ + c] = f2bf(h);
      }
    } else if constexpr (STAGE == S_GZR) {
      if (c < 800) {
        a.zgen[(size_t)bb*GEN_ + c] = sigm(v + a.bgzr[c]);
      } else if (c < 1600) {
        int u = c - 800;
        a.aghh[(size_t)bb*GEN_ + u] = f2bf(sigm(v + a.bgzr[c]) * a.genh[(size_t)bb*GEN_ + u]);
      } else if (c < 2400) {
        a.xhgen[(size_t)bb*GEN_ + (c-1600)] = v + a.bgzr[c];
      }
    } else if constexpr (STAGE == S_GHH) {
      if (c < 800) {
        float hh = tanhf(v + a.xhgen[(size_t)bb*GEN_ + c]);
        float z  = a.zgen[(size_t)bb*GEN_ + c];
        float h  = z * a.genh[(size_t)bb*GEN_ + c] + (1.f - z) * hh;
        h = fminf(fmaxf(h, -5.f), 5.f);
        a.genh[(size_t)bb*GEN_ + c] = h;
        a.genhb[(size_t)bb*GEN_ + c] = f2bf(h);
      }
    } else { // S_FAC
      if (c < 128) a.out[((size_t)bb*T_ + (T_-1))*FAC_ + c] = v;
    }
  }
}

__global__ __launch_bounds__(256, 2) void decoder_persist(PA a) {
  __shared__ unsigned short sA[2][2048];
  __shared__ unsigned short sB[2][2048];
  unsigned epoch = 0;
  for (int t = 0; t < T_; ++t) {
    do_stage<S_CZR, 1344, 21, 3>(a, t, sA, sB);  gbar(a.gs, ++epoch);
    do_stage<S_CHH,  416,  7, 1>(a, t, sA, sB);  gbar(a.gs, ++epoch);
    do_stage<S_GZR, 1216, 38, 5>(a, t, sA, sB);  gbar(a.gs, ++epoch);
    do_stage<S_GHH,  800, 13, 2>(a, t, sA, sB);  gbar(a.gs, ++epoch);
  }
  do_stage<S_FAC, 800, 2, 1>(a, T_-1, sA, sB);
}

// ---------------- host ----------------

extern "C" void kernel_launch(void* const* d_in, const int* in_sizes, int n_in,
                              void* d_out, int out_size, void* d_ws, size_t ws_size,
                              hipStream_t stream) {
  const float* ci      = (const float*)d_in[0];
  const float* ext     = (const float*)d_in[1];
  const float* geninit = (const float*)d_in[2];
  const float* conh0   = (const float*)d_in[3];
  const float* conK    = (const float*)d_in[4];
  const float* conR    = (const float*)d_in[5];
  const float* conb    = (const float*)d_in[6];
  const float* comW    = (const float*)d_in[7];
  const float* comb    = (const float*)d_in[8];
  const float* genK    = (const float*)d_in[11];
  const float* genR    = (const float*)d_in[12];
  const float* genb    = (const float*)d_in[13];
  const float* facW    = (const float*)d_in[14];
  float* out = (float*)d_out;

  char* ws = (char*)d_ws;
  size_t off = 0;
  auto alloc = [&](size_t bytes) -> void* {
    void* p = ws + off;
    off = (off + bytes + 255) & ~(size_t)255;
    return p;
  };
  unsigned short* wczr  = (unsigned short*)alloc(1344UL*1344*2);
  unsigned short* wchh  = (unsigned short*)alloc(448UL*416*2);
  unsigned short* wgzr  = (unsigned short*)alloc(2432UL*1216*2);
  unsigned short* wghh  = (unsigned short*)alloc(832UL*800*2);
  unsigned short* wfac  = (unsigned short*)alloc(128UL*800*2);
  float* facWn = (float*)alloc(800UL*128*4);
  float* tmp2  = (float*)alloc(800UL*1200*4);
  float* tmp1  = (float*)alloc(400UL*2400*4);
  float* bczr  = (float*)alloc(1344UL*4);
  float* bgzr  = (float*)alloc(2432UL*4);
  float* conh  = (float*)alloc((size_t)B_*CON_*4);
  float* genh  = (float*)alloc((size_t)B_*GEN_*4);
  unsigned short* genhb = (unsigned short*)alloc((size_t)B_*GEN_*2);
  unsigned short* agzr  = (unsigned short*)alloc((size_t)B_*CON_*2);
  unsigned short* achh  = (unsigned short*)alloc((size_t)B_*416*2);
  unsigned short* aghh  = (unsigned short*)alloc((size_t)B_*GEN_*2);
  float* zcon  = (float*)alloc((size_t)B_*CON_*4);
  float* xhcon = (float*)alloc((size_t)B_*CON_*4);
  float* zgen  = (float*)alloc((size_t)B_*GEN_*4);
  float* xhgen = (float*)alloc((size_t)B_*GEN_*4);
  unsigned short* cib  = (unsigned short*)alloc((size_t)B_*T_*CI_*2);
  unsigned short* extb = (unsigned short*)alloc((size_t)B_*T_*EXT_*2);
  unsigned short* zbuf = (unsigned short*)alloc(64UL*2);
  unsigned* gsync      = (unsigned*)alloc(320UL*4);
  (void)ws_size; (void)in_sizes; (void)n_in; (void)out_size;

  dim3 blk(256);
  k_facnorm<<<dim3(128), dim3(64), 0, stream>>>(facW, facWn);
  k_w2<<<dim3(5, 800), blk, 0, stream>>>(facWn, conK, tmp2);
  k_w1<<<dim3(10, 400), blk, 0, stream>>>(comW, genK, tmp1);
  k_cvt<<<dim3(1024), blk, 0, stream>>>(ci, ext, cib, extb);
  k_init<<<dim3(2048), blk, 0, stream>>>(conh0, geninit, conb, genb, comb, genK,
                                         bczr, bgzr, conh, agzr, genh, genhb, achh,
                                         zbuf, gsync);

  BTArgs bt;
  bt.conK = conK; bt.conR = conR; bt.genK = genK; bt.genR = genR;
  bt.facWn = facWn; bt.tmp1 = tmp1; bt.tmp2 = tmp2;
  bt.mode = 0; bt.K = 1344; bt.dst = wczr; k_buildT<<<dim3(21,21), blk, 0, stream>>>(bt);
  bt.mode = 1; bt.K = 416;  bt.dst = wchh; k_buildT<<<dim3(7,7),   blk, 0, stream>>>(bt);
  bt.mode = 2; bt.K = 1216; bt.dst = wgzr; k_buildT<<<dim3(19,38), blk, 0, stream>>>(bt);
  bt.mode = 3; bt.K = 800;  bt.dst = wghh; k_buildT<<<dim3(13,13), blk, 0, stream>>>(bt);
  bt.mode = 4; bt.K = 800;  bt.dst = wfac; k_buildT<<<dim3(13,2),  blk, 0, stream>>>(bt);

  PA pa;
  pa.cib = cib; pa.extb = extb;
  pa.wczr = wczr; pa.wchh = wchh; pa.wgzr = wgzr; pa.wghh = wghh; pa.wfac = wfac;
  pa.bczr = bczr; pa.bgzr = bgzr;
  pa.zcon = zcon; pa.xhcon = xhcon; pa.zgen = zgen; pa.xhgen = xhgen;
  pa.conh = conh; pa.genh = genh;
  pa.genhb = genhb; pa.agzr = agzr; pa.achh = achh; pa.aghh = aghh;
  pa.zbuf = zbuf; pa.out = out; pa.gs = gsync;

  decoder_persist<<<dim3(NBLK), blk, 0, stream>>>(pa);
}

// Round 3
// 17803.148 us; speedup vs baseline: 10.1711x; 10.1711x over previous
//
#include <hip/hip_runtime.h>
#include <cstdint>
#include <cstddef>

// Decoder (LFADS-like): B=512, T=200.
// Multi-kernel graph (4 dependent bf16-MFMA GEMM stages per step, 801 launches).
// Each stage: 64x64 tiles, 256 threads (4 waves, 2x2), MFMA fragments loaded
// DIRECTLY global->register (A and W^T are K-contiguous) -> no LDS, no
// barriers, latency hidden by #pragma unroll 4 (16 loads in flight per wave).
// XCD-aware mapping: bn ≡ blockIdx%8 so each weight column-slice stays in one
// XCD's L2 within a kernel.
// Precomposed weights:
//   W'  = com_W @ gen_K[:32]    (co_mean folded into generator input GEMM)
//   W'' = fac_Wn @ con_K[128:]  (factor path folded into controller GEMM;
//                                fac_Wn columns appended -> facs output free)

#define B_   512
#define T_   200
#define CI_  128
#define EXT_ 8
#define GEN_ 800
#define CON_ 400
#define CO_  32
#define FAC_ 128

typedef __attribute__((ext_vector_type(8))) short short8;
typedef __attribute__((ext_vector_type(4))) float f32x4;
typedef __attribute__((ext_vector_type(4))) unsigned short us4;

__device__ __forceinline__ unsigned short f2bf(float f) {
  unsigned int u = __float_as_uint(f);
  u += 0x7FFFu + ((u >> 16) & 1u);   // RNE
  return (unsigned short)(u >> 16);
}
__device__ __forceinline__ float sigm(float x) { return 1.0f / (1.0f + __expf(-x)); }

// ---------------- setup kernels ----------------

__global__ void k_facnorm(const float* __restrict__ facW, float* __restrict__ facWn) {
  int j = blockIdx.x;            // 0..127 (column)
  int l = threadIdx.x;           // 64 threads = 1 wave
  float s = 0.f;
  for (int k = l; k < GEN_; k += 64) { float v = facW[(size_t)k*FAC_ + j]; s += v*v; }
  #pragma unroll
  for (int off = 32; off > 0; off >>= 1) s += __shfl_down(s, off, 64);
  float inv = 1.0f / sqrtf(__shfl(s, 0, 64));
  for (int k = l; k < GEN_; k += 64) facWn[(size_t)k*FAC_ + j] = facW[(size_t)k*FAC_ + j] * inv;
}

// tmp2[kp][n] = sum_j facWn[kp][j] * conK[128+j][n]   (kp<800, n<1200)
__global__ void k_w2(const float* __restrict__ facWn, const float* __restrict__ conK,
                     float* __restrict__ tmp2) {
  int n = blockIdx.x*256 + threadIdx.x; if (n >= 1200) return;
  int kp = blockIdx.y;
  const float* fr = facWn + (size_t)kp*FAC_;
  float s = 0.f;
  for (int j = 0; j < FAC_; ++j) s = fmaf(fr[j], conK[(size_t)(CI_+j)*1200 + n], s);
  tmp2[(size_t)kp*1200 + n] = s;
}

// tmp1[k][n] = sum_j comW[k][j] * genK[j][n]   (k<400, n<2400)
__global__ void k_w1(const float* __restrict__ comW, const float* __restrict__ genK,
                     float* __restrict__ tmp1) {
  int n = blockIdx.x*256 + threadIdx.x; if (n >= 2400) return;
  int k = blockIdx.y;
  const float* cr = comW + (size_t)k*CO_;
  float s = 0.f;
  for (int j = 0; j < CO_; ++j) s = fmaf(cr[j], genK[(size_t)j*2400 + n], s);
  tmp1[(size_t)k*2400 + n] = s;
}

__global__ void k_cvt(const float* __restrict__ ci, const float* __restrict__ ext,
                      unsigned short* __restrict__ cib, unsigned short* __restrict__ extb) {
  const long n1 = (long)B_*T_*CI_/4;
  const long n2 = (long)B_*T_*EXT_/4;
  for (long i = blockIdx.x*(long)blockDim.x + threadIdx.x; i < n1+n2;
       i += (long)gridDim.x*blockDim.x) {
    if (i < n1) {
      float4 f = reinterpret_cast<const float4*>(ci)[i];
      us4 u; u.x=f2bf(f.x); u.y=f2bf(f.y); u.z=f2bf(f.z); u.w=f2bf(f.w);
      reinterpret_cast<us4*>(cib)[i] = u;
    } else {
      long k = i - n1;
      float4 f = reinterpret_cast<const float4*>(ext)[k];
      us4 u; u.x=f2bf(f.x); u.y=f2bf(f.y); u.z=f2bf(f.z); u.w=f2bf(f.w);
      reinterpret_cast<us4*>(extb)[k] = u;
    }
  }
}

__global__ void k_init(const float* __restrict__ conh0, const float* __restrict__ geninit,
                       const float* __restrict__ conb, const float* __restrict__ genb,
                       const float* __restrict__ comb, const float* __restrict__ genK,
                       float* __restrict__ bczr, float* __restrict__ bgzr,
                       float* __restrict__ conh, unsigned short* __restrict__ agzr,
                       float* __restrict__ genh, unsigned short* __restrict__ genhb,
                       unsigned short* __restrict__ achh,
                       unsigned short* __restrict__ zbuf) {
  const long R0=1344, R1=2432, R2=(long)B_*CON_, R3=(long)B_*CON_,
             R4=(long)B_*GEN_, R5=(long)B_*GEN_, R6=(long)B_*416, R7=64;
  const long total = R0+R1+R2+R3+R4+R5+R6+R7;
  for (long idx = blockIdx.x*(long)blockDim.x + threadIdx.x; idx < total;
       idx += (long)gridDim.x*blockDim.x) {
    long i = idx;
    if (i < R0) { bczr[i] = (i < 1200) ? conb[i] : 0.f; continue; }
    i -= R0;
    if (i < R1) {
      float s = 0.f;
      if (i < 2400) { s = genb[i]; for (int j=0;j<32;++j) s = fmaf(comb[j], genK[(size_t)j*2400 + i], s); }
      bgzr[i] = s; continue;
    }
    i -= R1;
    if (i < R2) { conh[i] = conh0[i % CON_]; continue; }
    i -= R2;
    if (i < R3) { agzr[i] = f2bf(conh0[i % CON_]); continue; }
    i -= R3;
    if (i < R4) { genh[i] = geninit[i]; continue; }
    i -= R4;
    if (i < R5) { genhb[i] = f2bf(geninit[i]); continue; }
    i -= R5;
    if (i < R6) { achh[i] = 0; continue; }
    i -= R6;
    zbuf[i] = 0;
  }
}

// build transposed bf16 weights: dst[n][k] = fetch(k, n)
struct BTArgs {
  int mode, K;
  const float* conK; const float* conR; const float* genK; const float* genR;
  const float* facWn; const float* tmp1; const float* tmp2;
  unsigned short* dst;
};

__device__ __forceinline__ float bt_fetch(const BTArgs& a, int k, int n) {
  switch (a.mode) {
    case 0: // W_czr^T: K=1344 (ci128|gen800|con416), N=1344 (z400|r400|xh400|fac128|pad)
      if (n < 1200) {
        if (k < 128)  return a.conK[(size_t)k*1200 + n];
        if (k < 928)  return a.tmp2[(size_t)(k-128)*1200 + n];
        if (k < 1328) return (n < 800) ? a.conR[(size_t)(k-928)*1200 + n] : 0.f;
        return 0.f;
      }
      if (n < 1328) return (k >= 128 && k < 928) ? a.facWn[(size_t)(k-128)*FAC_ + (n-1200)] : 0.f;
      return 0.f;
    case 1: // W_chh^T: con_R[:,800:1200]
      return (k < 400 && n < 400) ? a.conR[(size_t)k*1200 + 800 + n] : 0.f;
    case 2: // W_gzr^T: K=1216 (conh400|ext8|pad8|genh800), N=2432 (z800|r800|xh800|pad)
      if (n >= 2400) return 0.f;
      if (k < 400)  return a.tmp1[(size_t)k*2400 + n];
      if (k < 408)  return a.genK[(size_t)(32 + k - 400)*2400 + n];
      if (k < 416)  return 0.f;
      if (k < 1216) return (n < 1600) ? a.genR[(size_t)(k-416)*2400 + n] : 0.f;
      return 0.f;
    case 3: // W_ghh^T: gen_R[:,1600:2400]
      return (n < 800 && k < 800) ? a.genR[(size_t)k*2400 + 1600 + n] : 0.f;
    default: // fac_Wn^T [128][800]
      return (k < 800 && n < 128) ? a.facWn[(size_t)k*FAC_ + n] : 0.f;
  }
}

__global__ __launch_bounds__(256) void k_buildT(BTArgs a) {
  __shared__ float tile[64][65];
  int k0 = blockIdx.x*64, n0 = blockIdx.y*64;
  int tid = threadIdx.x;
  int rr = tid >> 2, cc = (tid & 3) * 16;
  #pragma unroll 4
  for (int i = 0; i < 16; ++i) tile[rr][cc+i] = bt_fetch(a, k0+rr, n0+cc+i);
  __syncthreads();
  int n = n0 + rr;
  if (k0 + cc < a.K) {    // K is a multiple of 16
    short8 v0, v1;
    #pragma unroll
    for (int i = 0; i < 8; ++i) v0[i] = (short)f2bf(tile[cc+i][rr]);
    #pragma unroll
    for (int i = 0; i < 8; ++i) v1[i] = (short)f2bf(tile[cc+8+i][rr]);
    *reinterpret_cast<short8*>(&a.dst[(size_t)n*a.K + k0 + cc])     = v0;
    *reinterpret_cast<short8*>(&a.dst[(size_t)n*a.K + k0 + cc + 8]) = v1;
  }
}

// ---------------- main GEMM stages (reg-direct MFMA) ----------------

struct PA {
  const unsigned short* cib; const unsigned short* extb;
  const unsigned short* wczr; const unsigned short* wchh; const unsigned short* wgzr;
  const unsigned short* wghh; const unsigned short* wfac;
  const float* bczr; const float* bgzr;
  float* zcon; float* xhcon; float* zgen; float* xhgen;
  float* conh; float* genh;
  unsigned short* genhb; unsigned short* agzr; unsigned short* achh; unsigned short* aghh;
  const unsigned short* zbuf;
  float* out;
};

enum { S_CZR=0, S_CHH=1, S_GZR=2, S_GHH=3, S_FAC=4 };

template<int STAGE, int K, int NN, int PER>
__global__ __launch_bounds__(256)
void gemm_stage(PA a, int t) {
  const int b = blockIdx.x;
  const int xcd = b & 7, j = b >> 3;
  const int bn = xcd + 8 * (j % PER);
  const int bm = j / PER;
  if (bn >= NN) return;

  const unsigned short* w =
      STAGE == S_CZR ? a.wczr : STAGE == S_CHH ? a.wchh :
      STAGE == S_GZR ? a.wgzr : STAGE == S_GHH ? a.wghh : a.wfac;

  const int tid = threadIdx.x, lane = tid & 63, wid = tid >> 6;
  const int wm = wid >> 1, wn = wid & 1;
  const int l15 = lane & 15, ko = (lane >> 4) * 8;

  const int rA0 = bm*64 + wm*32 + l15, rA1 = rA0 + 16;
  const int rB0 = bn*64 + wn*32 + l15, rB1 = rB0 + 16;
  const unsigned short* wp0 = w + (size_t)rB0*K + ko;
  const unsigned short* wp1 = w + (size_t)rB1*K + ko;

  // per-lane A base pointers per K-piece (selected per chunk by per-lane k)
  const unsigned short* A0[2]; const unsigned short* A1[2];
  const unsigned short* A2[2];
  const int rA[2] = { rA0, rA1 };
  #pragma unroll
  for (int mi = 0; mi < 2; ++mi) {
    if constexpr (STAGE == S_CZR) {
      A0[mi] = a.cib   + ((size_t)rA[mi]*T_ + t)*CI_;
      A1[mi] = a.genhb + (size_t)rA[mi]*GEN_ - 128;
      A2[mi] = a.agzr  + (size_t)rA[mi]*CON_ - 928;
    } else if constexpr (STAGE == S_CHH) {
      A0[mi] = a.achh + (size_t)rA[mi]*416;
      A1[mi] = A0[mi]; A2[mi] = A0[mi];
    } else if constexpr (STAGE == S_GZR) {
      A0[mi] = a.agzr  + (size_t)rA[mi]*CON_;
      A1[mi] = a.extb  + ((size_t)rA[mi]*T_ + t)*EXT_ - 400;
      A2[mi] = a.genhb + (size_t)rA[mi]*GEN_ - 416;
    } else { // S_GHH / S_FAC
      A0[mi] = (STAGE == S_GHH ? a.aghh : a.genhb) + (size_t)rA[mi]*GEN_;
      A1[mi] = A0[mi]; A2[mi] = A0[mi];
    }
  }

  f32x4 acc[2][2];
  #pragma unroll
  for (int i=0;i<2;++i)
    #pragma unroll
    for (int jj=0;jj<2;++jj) acc[i][jj] = (f32x4){0.f,0.f,0.f,0.f};

  constexpr int NK = K / 32;
  #pragma unroll 4
  for (int kt = 0; kt < NK; ++kt) {
    const int k = kt*32 + ko;
    short8 av[2], bv[2];
    bv[0] = *reinterpret_cast<const short8*>(wp0 + kt*32);
    bv[1] = *reinterpret_cast<const short8*>(wp1 + kt*32);
    #pragma unroll
    for (int mi = 0; mi < 2; ++mi) {
      const unsigned short* p;
      if constexpr (STAGE == S_CZR) {
        p = k < 128 ? A0[mi] + k : k < 928 ? A1[mi] + k
          : k < 1328 ? A2[mi] + k : a.zbuf;
      } else if constexpr (STAGE == S_GZR) {
        p = k < 400 ? A0[mi] + k : k < 408 ? A1[mi] + k
          : k < 416 ? a.zbuf : A2[mi] + k;
      } else {
        p = A0[mi] + k;
      }
      av[mi] = *reinterpret_cast<const short8*>(p);
    }
    acc[0][0] = __builtin_amdgcn_mfma_f32_16x16x32_bf16(av[0], bv[0], acc[0][0], 0,0,0);
    acc[0][1] = __builtin_amdgcn_mfma_f32_16x16x32_bf16(av[0], bv[1], acc[0][1], 0,0,0);
    acc[1][0] = __builtin_amdgcn_mfma_f32_16x16x32_bf16(av[1], bv[0], acc[1][0], 0,0,0);
    acc[1][1] = __builtin_amdgcn_mfma_f32_16x16x32_bf16(av[1], bv[1], acc[1][1], 0,0,0);
  }

  const int lrow = (lane >> 4) * 4;
  #pragma unroll
  for (int mi=0; mi<2; ++mi)
  #pragma unroll
  for (int ni=0; ni<2; ++ni)
  #pragma unroll
  for (int jj=0; jj<4; ++jj) {
    int bb = bm*64 + wm*32 + mi*16 + lrow + jj;
    int c  = bn*64 + wn*32 + ni*16 + l15;
    float v = acc[mi][ni][jj];
    if constexpr (STAGE == S_CZR) {
      if (c < 400) {
        a.zcon[(size_t)bb*CON_ + c] = sigm(v + a.bczr[c]);
      } else if (c < 800) {
        int u = c - 400;
        a.achh[(size_t)bb*416 + u] = f2bf(sigm(v + a.bczr[c]) * a.conh[(size_t)bb*CON_ + u]);
      } else if (c < 1200) {
        a.xhcon[(size_t)bb*CON_ + (c-800)] = v + a.bczr[c];
      } else if (c < 1328) {
        if (t > 0) a.out[((size_t)bb*T_ + (t-1))*FAC_ + (c-1200)] = v;
      }
    } else if constexpr (STAGE == S_CHH) {
      if (c < 400) {
        float hh = tanhf(v + a.xhcon[(size_t)bb*CON_ + c]);
        float z  = a.zcon[(size_t)bb*CON_ + c];
        float h  = z * a.conh[(size_t)bb*CON_ + c] + (1.f - z) * hh;
        h = fminf(fmaxf(h, -5.f), 5.f);
        a.conh[(size_t)bb*CON_ + c] = h;
        a.agzr[(size_t)bb*CON_ + c] = f2bf(h);
      }
    } else if constexpr (STAGE == S_GZR) {
      if (c < 800) {
        a.zgen[(size_t)bb*GEN_ + c] = sigm(v + a.bgzr[c]);
      } else if (c < 1600) {
        int u = c - 800;
        a.aghh[(size_t)bb*GEN_ + u] = f2bf(sigm(v + a.bgzr[c]) * a.genh[(size_t)bb*GEN_ + u]);
      } else if (c < 2400) {
        a.xhgen[(size_t)bb*GEN_ + (c-1600)] = v + a.bgzr[c];
      }
    } else if constexpr (STAGE == S_GHH) {
      if (c < 800) {
        float hh = tanhf(v + a.xhgen[(size_t)bb*GEN_ + c]);
        float z  = a.zgen[(size_t)bb*GEN_ + c];
        float h  = z * a.genh[(size_t)bb*GEN_ + c] + (1.f - z) * hh;
        h = fminf(fmaxf(h, -5.f), 5.f);
        a.genh[(size_t)bb*GEN_ + c] = h;
        a.genhb[(size_t)bb*GEN_ + c] = f2bf(h);
      }
    } else { // S_FAC
      if (c < 128) a.out[((size_t)bb*T_ + (T_-1))*FAC_ + c] = v;
    }
  }
}

// ---------------- host ----------------

extern "C" void kernel_launch(void* const* d_in, const int* in_sizes, int n_in,
                              void* d_out, int out_size, void* d_ws, size_t ws_size,
                              hipStream_t stream) {
  const float* ci      = (const float*)d_in[0];
  const float* ext     = (const float*)d_in[1];
  const float* geninit = (const float*)d_in[2];
  const float* conh0   = (const float*)d_in[3];
  const float* conK    = (const float*)d_in[4];
  const float* conR    = (const float*)d_in[5];
  const float* conb    = (const float*)d_in[6];
  const float* comW    = (const float*)d_in[7];
  const float* comb    = (const float*)d_in[8];
  const float* genK    = (const float*)d_in[11];
  const float* genR    = (const float*)d_in[12];
  const float* genb    = (const float*)d_in[13];
  const float* facW    = (const float*)d_in[14];
  float* out = (float*)d_out;

  char* ws = (char*)d_ws;
  size_t off = 0;
  auto alloc = [&](size_t bytes) -> void* {
    void* p = ws + off;
    off = (off + bytes + 255) & ~(size_t)255;
    return p;
  };
  unsigned short* wczr  = (unsigned short*)alloc(1344UL*1344*2);
  unsigned short* wchh  = (unsigned short*)alloc(448UL*416*2);
  unsigned short* wgzr  = (unsigned short*)alloc(2432UL*1216*2);
  unsigned short* wghh  = (unsigned short*)alloc(832UL*800*2);
  unsigned short* wfac  = (unsigned short*)alloc(128UL*800*2);
  float* facWn = (float*)alloc(800UL*128*4);
  float* tmp2  = (float*)alloc(800UL*1200*4);
  float* tmp1  = (float*)alloc(400UL*2400*4);
  float* bczr  = (float*)alloc(1344UL*4);
  float* bgzr  = (float*)alloc(2432UL*4);
  float* conh  = (float*)alloc((size_t)B_*CON_*4);
  float* genh  = (float*)alloc((size_t)B_*GEN_*4);
  unsigned short* genhb = (unsigned short*)alloc((size_t)B_*GEN_*2);
  unsigned short* agzr  = (unsigned short*)alloc((size_t)B_*CON_*2);
  unsigned short* achh  = (unsigned short*)alloc((size_t)B_*416*2);
  unsigned short* aghh  = (unsigned short*)alloc((size_t)B_*GEN_*2);
  float* zcon  = (float*)alloc((size_t)B_*CON_*4);
  float* xhcon = (float*)alloc((size_t)B_*CON_*4);
  float* zgen  = (float*)alloc((size_t)B_*GEN_*4);
  float* xhgen = (float*)alloc((size_t)B_*GEN_*4);
  unsigned short* cib  = (unsigned short*)alloc((size_t)B_*T_*CI_*2);
  unsigned short* extb = (unsigned short*)alloc((size_t)B_*T_*EXT_*2);
  unsigned short* zbuf = (unsigned short*)alloc(64UL*2);
  (void)ws_size; (void)in_sizes; (void)n_in; (void)out_size;

  dim3 blk(256);
  k_facnorm<<<dim3(128), dim3(64), 0, stream>>>(facW, facWn);
  k_w2<<<dim3(5, 800), blk, 0, stream>>>(facWn, conK, tmp2);
  k_w1<<<dim3(10, 400), blk, 0, stream>>>(comW, genK, tmp1);
  k_cvt<<<dim3(1024), blk, 0, stream>>>(ci, ext, cib, extb);
  k_init<<<dim3(2048), blk, 0, stream>>>(conh0, geninit, conb, genb, comb, genK,
                                         bczr, bgzr, conh, agzr, genh, genhb, achh,
                                         zbuf);

  BTArgs bt;
  bt.conK = conK; bt.conR = conR; bt.genK = genK; bt.genR = genR;
  bt.facWn = facWn; bt.tmp1 = tmp1; bt.tmp2 = tmp2;
  bt.mode = 0; bt.K = 1344; bt.dst = wczr; k_buildT<<<dim3(21,21), blk, 0, stream>>>(bt);
  bt.mode = 1; bt.K = 416;  bt.dst = wchh; k_buildT<<<dim3(7,7),   blk, 0, stream>>>(bt);
  bt.mode = 2; bt.K = 1216; bt.dst = wgzr; k_buildT<<<dim3(19,38), blk, 0, stream>>>(bt);
  bt.mode = 3; bt.K = 800;  bt.dst = wghh; k_buildT<<<dim3(13,13), blk, 0, stream>>>(bt);
  bt.mode = 4; bt.K = 800;  bt.dst = wfac; k_buildT<<<dim3(13,2),  blk, 0, stream>>>(bt);

  PA pa;
  pa.cib = cib; pa.extb = extb;
  pa.wczr = wczr; pa.wchh = wchh; pa.wgzr = wgzr; pa.wghh = wghh; pa.wfac = wfac;
  pa.bczr = bczr; pa.bgzr = bgzr;
  pa.zcon = zcon; pa.xhcon = xhcon; pa.zgen = zgen; pa.xhgen = xhgen;
  pa.conh = conh; pa.genh = genh;
  pa.genhb = genhb; pa.agzr = agzr; pa.achh = achh; pa.aghh = aghh;
  pa.zbuf = zbuf; pa.out = out;

  for (int t = 0; t < T_; ++t) {
    gemm_stage<S_CZR, 1344, 21, 3><<<dim3(192), blk, 0, stream>>>(pa, t);
    gemm_stage<S_CHH,  416,  7, 1><<<dim3(64),  blk, 0, stream>>>(pa, t);
    gemm_stage<S_GZR, 1216, 38, 5><<<dim3(320), blk, 0, stream>>>(pa, t);
    gemm_stage<S_GHH,  800, 13, 2><<<dim3(128), blk, 0, stream>>>(pa, t);
  }
  gemm_stage<S_FAC, 800, 2, 1><<<dim3(64), blk, 0, stream>>>(pa, T_-1);
}